// Round 17
// baseline (367.165 us; speedup 1.0000x reference)
//
#include <hip/hip_runtime.h>
#include <hip/hip_bf16.h>

#define T_ 768
#define A_ 24
#define S_ 576
#define Q_ 32
#define K_ 128
#define C_ 128
#define H_ 4
#define DH_ 32
#define L_ 3
#define PAIR_ 16
#define PTC_ 384
#define FF_ 256
#define SQ_ (S_*Q_)
#define SK_ (S_*K_)

typedef __attribute__((ext_vector_type(8))) short bf16x8;
typedef __attribute__((ext_vector_type(4))) short bf16x4;
typedef __attribute__((ext_vector_type(4))) float f32x4;
typedef unsigned short ushort_t;

#define MFMA(a,b,c) __builtin_amdgcn_mfma_f32_16x16x32_bf16(a,b,c,0,0,0)

__device__ inline unsigned short f2b(float f) {
    union { float f; unsigned u; } v; v.f = f;
    unsigned u = v.u;
    return (unsigned short)((u + 0x7FFFu + ((u >> 16) & 1u)) >> 16);
}
__device__ inline float b2f(unsigned short b) {
    union { unsigned u; float f; } v; v.u = ((unsigned)b) << 16;
    return v.f;
}
__device__ inline float dot4(float4 a, float4 b) {
    return a.x*b.x + a.y*b.y + a.z*b.z + a.w*b.w;
}

// load one MFMA fragment (8 bf16 along k) from swizzled LDS tile with row-length KD
template<int KD>
__device__ inline bf16x8 ldfrag(const unsigned short* lds, int row, int k) {
    int byte = ((row*KD + k)*2) ^ ((row & 7) << 4);
    return *(const bf16x8*)((const char*)lds + byte);
}

// ---- LN over 64 rows (4 threads/row), from GLOBAL f32 -> swizzled LDS (+opt global bf16) ----
__device__ inline void ln_rows64(const float* __restrict__ x, size_t r0,
                                 const float* __restrict__ s, const float* __restrict__ b,
                                 unsigned short* at, ushort_t* __restrict__ xn16_opt) {
    int t = threadIdx.x;
    int row = t >> 2, q = t & 3;
    size_t gr = r0 + row;
    float v[32];
    const float4* xp = (const float4*)(x + gr*C_ + q*32);
    #pragma unroll
    for (int i = 0; i < 8; i++) {
        float4 f = xp[i];
        v[i*4]=f.x; v[i*4+1]=f.y; v[i*4+2]=f.z; v[i*4+3]=f.w;
    }
    float sum = 0.f;
    #pragma unroll
    for (int i = 0; i < 32; i++) sum += v[i];
    sum += __shfl_xor(sum, 1); sum += __shfl_xor(sum, 2);
    float mean = sum * (1.0f/C_);
    float sq = 0.f;
    #pragma unroll
    for (int i = 0; i < 32; i++) { float d = v[i]-mean; sq += d*d; }
    sq += __shfl_xor(sq, 1); sq += __shfl_xor(sq, 2);
    float rs = rsqrtf(sq * (1.0f/C_) + 1e-5f);
    #pragma unroll
    for (int i8 = 0; i8 < 4; i8++) {
        int c0 = q*32 + i8*8;
        const float4* sp = (const float4*)(s + c0);
        const float4* bp = (const float4*)(b + c0);
        float4 s0 = sp[0], s1 = sp[1], b0 = bp[0], b1 = bp[1];
        bf16x8 o;
        o[0] = (short)f2b((v[i8*8+0]-mean)*rs*s0.x + b0.x);
        o[1] = (short)f2b((v[i8*8+1]-mean)*rs*s0.y + b0.y);
        o[2] = (short)f2b((v[i8*8+2]-mean)*rs*s0.z + b0.z);
        o[3] = (short)f2b((v[i8*8+3]-mean)*rs*s0.w + b0.w);
        o[4] = (short)f2b((v[i8*8+4]-mean)*rs*s1.x + b1.x);
        o[5] = (short)f2b((v[i8*8+5]-mean)*rs*s1.y + b1.y);
        o[6] = (short)f2b((v[i8*8+6]-mean)*rs*s1.z + b1.z);
        o[7] = (short)f2b((v[i8*8+7]-mean)*rs*s1.w + b1.w);
        int byte = ((row*C_ + c0)*2) ^ ((row & 7) << 4);
        *(bf16x8*)((char*)at + byte) = o;
        if (xn16_opt) *(bf16x8*)(xn16_opt + gr*C_ + c0) = o;
    }
}

// ---------------- weight transpose helper ----------------
__device__ inline void wtr(const float* __restrict__ src, ushort_t* __restrict__ dst,
                           int e, int KD, int ND) {
    int l = e / (KD*ND), r = e % (KD*ND);
    int n = r / KD, k = r % KD;
    dst[e] = f2b(src[(size_t)l*KD*ND + (size_t)k*ND + n]);
}

#define NB_WPREP ((4*L_*C_*C_ + 2*L_*C_*FF_ + C_*PTC_)/256)
#define NB_INIT  ((SQ_*C_)/256)
#define NB_KSC   ((SK_*C_)/1024)

// ---------------- bias precompute (STANDALONE — needs full VGPR budget for 8x float4) ----------------
__global__ __launch_bounds__(256) void k_bias(const float* __restrict__ pair,
                                              const float* __restrict__ wpair,
                                              ushort_t* __restrict__ bias16) {
    __shared__ float wp[L_*H_][PAIR_];
    int t = threadIdx.x;
    if (t < L_*H_*PAIR_) {
        int lh = t >> 4, p = t & 15;
        wp[lh][p] = wpair[(lh>>2)*PAIR_*H_ + p*H_ + (lh&3)];
    }
    __syncthreads();
    int s = blockIdx.x >> 3, qg = blockIdx.x & 7;
    int qq = qg*4 + (t >> 6);
    int kk0 = (t & 63)*2;
    const float4* pp = (const float4*)(pair + (((size_t)s*Q_ + qq)*K_ + kk0)*PAIR_);
    float4 pa0 = pp[0], pa1 = pp[1], pa2 = pp[2], pa3 = pp[3];
    float4 pb0 = pp[4], pb1 = pp[5], pb2 = pp[6], pb3 = pp[7];
    #pragma unroll
    for (int lh = 0; lh < L_*H_; lh++) {
        const float4* w4 = (const float4*)&wp[lh][0];
        float4 w0 = w4[0], w1 = w4[1], w2 = w4[2], w3 = w4[3];
        float a = dot4(pa0,w0) + dot4(pa1,w1) + dot4(pa2,w2) + dot4(pa3,w3);
        float b = dot4(pb0,w0) + dot4(pb1,w1) + dot4(pb2,w2) + dot4(pb3,w3);
        unsigned pack = (unsigned)f2b(a) | ((unsigned)f2b(b) << 16);
        int l = lh >> 2, h = lh & 3;
        *(unsigned*)(bias16 + (((size_t)l*S_ + s)*H_ + h)*(Q_*K_) + qq*K_ + kk0) = pack;
    }
}

// ---------------- fused prep: weight transposes (incl. w_aggr) | init x | ksc->bf16 ----------------
__global__ __launch_bounds__(256) void k_prep(
    const float* __restrict__ wq, const float* __restrict__ wk, const float* __restrict__ wv,
    const float* __restrict__ w1, const float* __restrict__ w2, const float* __restrict__ wo,
    const float* __restrict__ w_aggr,
    ushort_t* __restrict__ wqT, ushort_t* __restrict__ wkT, ushort_t* __restrict__ wvT,
    ushort_t* __restrict__ w1T, ushort_t* __restrict__ w2T, ushort_t* __restrict__ woT,
    ushort_t* __restrict__ waT,
    const int* __restrict__ a2q_idx, const int* __restrict__ a2q_mask,
    const int* __restrict__ qmask, const float* __restrict__ ta_act,
    const float* __restrict__ qsc, const float* __restrict__ w_pos, float* __restrict__ x,
    const float* __restrict__ ksc, ushort_t* __restrict__ ksc16) {
    int blk = blockIdx.x, t = threadIdx.x;
    if (blk < NB_WPREP) {
        int e = blk * 256 + t;
        const int s_cc = L_*C_*C_;
        const int s_cf = L_*C_*FF_;
        if (e < s_cc)      { wtr(wq, wqT, e, C_, C_); return; }
        e -= s_cc;
        if (e < s_cc)      { wtr(wk, wkT, e, C_, C_); return; }
        e -= s_cc;
        if (e < s_cc)      { wtr(wv, wvT, e, C_, C_); return; }
        e -= s_cc;
        if (e < s_cf)      { wtr(w1, w1T, e, C_, FF_); return; }
        e -= s_cf;
        if (e < s_cf)      { wtr(w2, w2T, e, FF_, C_); return; }
        e -= s_cf;
        if (e < s_cc)      { wtr(wo, woT, e, C_, C_); return; }
        e -= s_cc;
        wtr(w_aggr, waT, e, C_, PTC_);
        return;
    }
    blk -= NB_WPREP;
    if (blk < NB_INIT) {
        int i = blk * 256 + t;
        int r = i / C_, c = i % C_;
        float v = 0.f;
        if (a2q_mask[r]) {
            int idx = a2q_idx[r];
            float p0 = ta_act[idx*3+0], p1 = ta_act[idx*3+1], p2 = ta_act[idx*3+2];
            v = p0 * w_pos[c] + p1 * w_pos[C_+c] + p2 * w_pos[2*C_+c];
        }
        v *= (float)qmask[r];
        x[i] = v + qsc[i];
        return;
    }
    blk -= NB_INIT;
    {
        int e4 = blk * 256 + t;
        float4 f = ((const float4*)ksc)[e4];
        bf16x4 o;
        o[0] = (short)f2b(f.x); o[1] = (short)f2b(f.y);
        o[2] = (short)f2b(f.z); o[3] = (short)f2b(f.w);
        *(bf16x4*)(ksc16 + (size_t)e4*4) = o;
    }
}

// ---------------- LN1 + q projection fused (layer 0 only) ----------------
__global__ __launch_bounds__(256) void k_lnqproj(const float* __restrict__ x,
                                                 const float* __restrict__ s, const float* __restrict__ b,
                                                 const ushort_t* __restrict__ wqT,
                                                 ushort_t* __restrict__ xn16,
                                                 ushort_t* __restrict__ qb16) {
    __shared__ unsigned short at[64*C_];   // 16 KB
    size_t r0 = (size_t)blockIdx.x * 64;
    ln_rows64(x, r0, s, b, at, xn16);
    __syncthreads();
    int t = threadIdx.x, wid = t>>6, lane = t&63, lr = lane&15, g = lane>>4;
    int mh = (wid&1)*32, nh = (wid>>1)*64;
    f32x4 acc[2][4] = {};
    #pragma unroll
    for (int ks = 0; ks < 4; ks++) {
        int ka = ks*32 + g*8;
        bf16x8 a0 = ldfrag<C_>(at, mh + lr, ka);
        bf16x8 a1 = ldfrag<C_>(at, mh + 16 + lr, ka);
        #pragma unroll
        for (int nt = 0; nt < 4; nt++) {
            bf16x8 bb = *(const bf16x8*)(wqT + (size_t)(nh + nt*16 + lr)*C_ + ka);
            acc[0][nt] = MFMA(a0, bb, acc[0][nt]);
            acc[1][nt] = MFMA(a1, bb, acc[1][nt]);
        }
    }
    const float scale = 0.17677669529663687f;  // 1/sqrt(32)
    #pragma unroll
    for (int mt = 0; mt < 2; mt++)
    #pragma unroll
    for (int nt = 0; nt < 4; nt++)
    #pragma unroll
    for (int r = 0; r < 4; r++) {
        int row = (int)r0 + mh + mt*16 + g*4 + r;
        int col = nh + nt*16 + lr;
        int s2 = row>>5, qq = row&31, h = col>>5, dd = col&31;
        qb16[(((size_t)s2*H_ + h)*Q_ + qq)*DH_ + dd] = f2b(acc[mt][nt][r] * scale);
    }
}

// ------- keys gather (16 KB LDS) + K/V projection; weights direct from global -------
__global__ __launch_bounds__(256) void k_kv_m(const ushort_t* __restrict__ xn16,
    const int* __restrict__ q2k_idx, const int* __restrict__ q2k_mask,
    const ushort_t* __restrict__ ksc16,
    const ushort_t* __restrict__ wkT, const ushort_t* __restrict__ wvT,
    ushort_t* __restrict__ kb16, ushort_t* __restrict__ vT16) {
    __shared__ unsigned short at[64*C_];   // 16 KB, swizzled
    int t = threadIdx.x, wid = t>>6, lane = t&63, lr = lane&15, g = lane>>4;
    int r0 = blockIdx.x * 64;
    for (int e8 = t; e8 < 64*(C_/8); e8 += 256) {
        int row = e8 >> 4, c8 = (e8 & 15)*8;
        int gr = r0 + row;
        bf16x8 kc8 = *(const bf16x8*)(ksc16 + (size_t)gr*C_ + c8);
        bf16x8 o;
        if (q2k_mask[gr]) {
            bf16x8 xv = *(const bf16x8*)(xn16 + (size_t)q2k_idx[gr]*C_ + c8);
            #pragma unroll
            for (int j = 0; j < 8; j++)
                o[j] = (short)f2b(b2f((unsigned short)xv[j]) + b2f((unsigned short)kc8[j]));
        } else {
            o = kc8;
        }
        int byte = ((row*C_ + c8)*2) ^ ((row & 7) << 4);
        *(bf16x8*)((char*)at + byte) = o;
    }
    __syncthreads();
    int mh = (wid&1)*32, nh = (wid>>1)*64;
    f32x4 acc[2][4][2] = {};
    #pragma unroll
    for (int ks = 0; ks < 4; ks++) {
        int ka = ks*32 + g*8;
        bf16x8 a0 = ldfrag<C_>(at, mh + lr, ka);
        bf16x8 a1 = ldfrag<C_>(at, mh + 16 + lr, ka);
        #pragma unroll
        for (int nt = 0; nt < 4; nt++) {
            bf16x8 bk = *(const bf16x8*)(wkT + (size_t)(nh + nt*16 + lr)*C_ + ka);
            bf16x8 bv = *(const bf16x8*)(wvT + (size_t)(nh + nt*16 + lr)*C_ + ka);
            acc[0][nt][0] = MFMA(a0, bk, acc[0][nt][0]);
            acc[1][nt][0] = MFMA(a1, bk, acc[1][nt][0]);
            acc[0][nt][1] = MFMA(a0, bv, acc[0][nt][1]);
            acc[1][nt][1] = MFMA(a1, bv, acc[1][nt][1]);
        }
    }
    #pragma unroll
    for (int mt = 0; mt < 2; mt++)
    #pragma unroll
    for (int nt = 0; nt < 4; nt++)
    #pragma unroll
    for (int r = 0; r < 4; r++) {
        int row = r0 + mh + mt*16 + g*4 + r;
        int col = nh + nt*16 + lr;
        int s = row>>7, kk = row&127, h = col>>5, dd = col&31;
        kb16[(((size_t)s*H_ + h)*K_ + kk)*DH_ + dd] = f2b(acc[mt][nt][0][r]);
        vT16[(((size_t)s*H_ + h)*DH_ + dd)*K_ + kk] = f2b(acc[mt][nt][1][r]);
    }
}

// ==== MEGA: attn + residual(regs) + LN2 + FF1 + FF2 (+ LN1'/qproj' or final mask) ====
__global__ __launch_bounds__(256) void k_mega(
    const ushort_t* __restrict__ qb16_in, const ushort_t* __restrict__ kb16,
    const ushort_t* __restrict__ vT16, const ushort_t* __restrict__ bias16,
    const int* __restrict__ kmask_g, const ushort_t* __restrict__ woT16,
    float* __restrict__ x,
    const float* __restrict__ ln2_s, const float* __restrict__ ln2_b,
    const ushort_t* __restrict__ w1T, const ushort_t* __restrict__ w2T,
    const float* __restrict__ ln1_s, const float* __restrict__ ln1_b,
    const ushort_t* __restrict__ wqT_next,
    ushort_t* __restrict__ xn16, ushort_t* __restrict__ qb16_out,
    const int* __restrict__ qmask_opt, float* __restrict__ skip_opt) {
    __shared__ __align__(16) char smem[40960];
    unsigned short* BP    = (unsigned short*)smem;            // 4 planes x 8 KB (bias, then P)
    unsigned short* O_lds = (unsigned short*)(smem + 32768);  // 8 KB
    unsigned short* at    = (unsigned short*)smem;            // alias plane 0 (post-PV)
    unsigned short* fft   = (unsigned short*)(smem + 8192);   // alias planes 1-2 (post-PV)
    float*          stats = (float*)(smem + 32768);           // [32][8] after wo consumed O_lds

    int s = blockIdx.x, t = threadIdx.x;
    int w = t>>6, lane = t&63, lr = lane&15, g = lane>>4;

    // ---- early x prefetch (residual; HBM latency hides under attention) ----
    float xres[2][2][4];
    #pragma unroll
    for (int mt = 0; mt < 2; mt++)
    #pragma unroll
    for (int nt = 0; nt < 2; nt++)
    #pragma unroll
    for (int r = 0; r < 4; r++) {
        int row = mt*16 + g*4 + r;
        int col = w*32 + nt*16 + lr;
        xres[mt][nt][r] = x[((size_t)s*Q_ + row)*C_ + col];
    }

    // ---- Phase A: attention ----
    {
        const ushort_t* bb = bias16 + (size_t)s*H_*Q_*K_;
        for (int e8 = t; e8 < H_*Q_*K_/8; e8 += 256) {
            int h = e8 >> 9, rem = e8 & 511;
            int qq = rem >> 4, kk0 = (rem & 15)*8;
            bf16x8 v = *(const bf16x8*)(bb + h*(Q_*K_) + qq*K_ + kk0);
            int byte = ((qq*K_ + kk0)*2) ^ (((qq>>2)&3)<<5);
            *(bf16x8*)((char*)(BP + h*(Q_*K_)) + byte) = v;
        }
    }

    const ushort_t* qbase = qb16_in + ((size_t)(s*H_ + w)*Q_)*DH_;
    bf16x8 aq0 = *(const bf16x8*)(qbase + (size_t)lr*DH_ + g*8);
    bf16x8 aq1 = *(const bf16x8*)(qbase + (size_t)(16+lr)*DH_ + g*8);

    const ushort_t* kbase = kb16 + ((size_t)(s*H_ + w)*K_)*DH_;
    f32x4 acc[2][8] = {};
    #pragma unroll
    for (int nt = 0; nt < 8; nt++) {
        bf16x8 b = *(const bf16x8*)(kbase + (size_t)(nt*16+lr)*DH_ + g*8);
        acc[0][nt] = MFMA(aq0, b, acc[0][nt]);
        acc[1][nt] = MFMA(aq1, b, acc[1][nt]);
    }

    float km[8];
    #pragma unroll
    for (int nt = 0; nt < 8; nt++) km[nt] = (kmask_g[s*K_ + nt*16 + lr] - 1.0f) * 1e9f;

    __syncthreads();   // bias staged

    unsigned short* Pb = BP + w*(Q_*K_);
    #pragma unroll
    for (int mt = 0; mt < 2; mt++)
    #pragma unroll
    for (int r = 0; r < 4; r++) {
        int qq = mt*16 + g*4 + r;
        #pragma unroll
        for (int nt = 0; nt < 8; nt++) {
            int byte = ((qq*K_ + nt*16 + lr)*2) ^ (((qq>>2)&3)<<5);
            acc[mt][nt][r] += b2f(*(unsigned short*)((char*)Pb + byte)) + km[nt];
        }
    }

    float inv[2][4];
    #pragma unroll
    for (int mt = 0; mt < 2; mt++)
    #pragma unroll
    for (int r = 0; r < 4; r++) {
        float mx = acc[mt][0][r];
        #pragma unroll
        for (int nt = 1; nt < 8; nt++) mx = fmaxf(mx, acc[mt][nt][r]);
        #pragma unroll
        for (int m = 1; m <= 8; m <<= 1) mx = fmaxf(mx, __shfl_xor(mx, m));
        float sum = 0.f;
        #pragma unroll
        for (int nt = 0; nt < 8; nt++) {
            float e = __expf(acc[mt][nt][r] - mx);
            acc[mt][nt][r] = e;
            sum += e;
        }
        #pragma unroll
        for (int m = 1; m <= 8; m <<= 1) sum += __shfl_xor(sum, m);
        inv[mt][r] = 1.0f / sum;
    }

    #pragma unroll
    for (int mt = 0; mt < 2; mt++)
    #pragma unroll
    for (int r = 0; r < 4; r++) {
        int row = mt*16 + g*4 + r;
        #pragma unroll
        for (int nt = 0; nt < 8; nt++) {
            int byte = ((row*K_ + nt*16 + lr)*2) ^ ((row & 7) << 4);
            *(unsigned short*)((char*)Pb + byte) = f2b(acc[mt][nt][r]);
        }
    }

    const ushort_t* vbase = vT16 + ((size_t)(s*H_ + w)*DH_)*K_;
    f32x4 po[2][2] = {};
    #pragma unroll
    for (int ks = 0; ks < 4; ks++) {
        int kk0 = ks*32 + g*8;
        bf16x8 a0 = ldfrag<K_>(Pb, lr, kk0);
        bf16x8 a1 = ldfrag<K_>(Pb, 16 + lr, kk0);
        #pragma unroll
        for (int nt = 0; nt < 2; nt++) {
            bf16x8 b = *(const bf16x8*)(vbase + (size_t)(nt*16+lr)*K_ + kk0);
            po[0][nt] = MFMA(a0, b, po[0][nt]);
            po[1][nt] = MFMA(a1, b, po[1][nt]);
        }
    }

    #pragma unroll
    for (int mt = 0; mt < 2; mt++)
    #pragma unroll
    for (int nt = 0; nt < 2; nt++)
    #pragma unroll
    for (int r = 0; r < 4; r++) {
        int row = mt*16 + g*4 + r;
        int col = w*32 + nt*16 + lr;
        int byte = ((row*C_ + col)*2) ^ ((row & 7) << 4);
        *(unsigned short*)((char*)O_lds + byte) = f2b(po[mt][nt][r] * inv[mt][r]);
    }
    __syncthreads();

    f32x4 fo[2][2] = {};
    #pragma unroll
    for (int ks = 0; ks < 4; ks++) {
        int k0 = ks*32 + g*8;
        bf16x8 a0 = ldfrag<C_>(O_lds, lr, k0);
        bf16x8 a1 = ldfrag<C_>(O_lds, 16 + lr, k0);
        #pragma unroll
        for (int nt = 0; nt < 2; nt++) {
            bf16x8 b = *(const bf16x8*)(woT16 + (size_t)(w*32 + nt*16 + lr)*C_ + k0);
            fo[0][nt] = MFMA(a0, b, fo[0][nt]);
            fo[1][nt] = MFMA(a1, b, fo[1][nt]);
        }
    }

    // ---- Phase B: residual (x preloaded) ----
    #pragma unroll
    for (int mt = 0; mt < 2; mt++)
    #pragma unroll
    for (int nt = 0; nt < 2; nt++)
    #pragma unroll
    for (int r = 0; r < 4; r++) {
        xres[mt][nt][r] += fo[mt][nt][r];
    }
    __syncthreads();   // all PV/wo LDS reads done -> BP + O_lds reusable

    int col0 = w*32 + lr, col1 = w*32 + 16 + lr;

    // ================== LN2 (register-space) -> at ==================
    {
        float ps[2][4], pq[2][4];
        #pragma unroll
        for (int mt = 0; mt < 2; mt++)
        #pragma unroll
        for (int r = 0; r < 4; r++) {
            float a = xres[mt][0][r], b = xres[mt][1][r];
            float sum = a + b, sq = a*a + b*b;
            #pragma unroll
            for (int m = 1; m <= 8; m <<= 1) { sum += __shfl_xor(sum, m); sq += __shfl_xor(sq, m); }
            ps[mt][r] = sum; pq[mt][r] = sq;
        }
        if (lr == 0) {
            #pragma unroll
            for (int mt = 0; mt < 2; mt++)
            #pragma unroll
            for (int r = 0; r < 4; r++) {
                int row = mt*16 + g*4 + r;
                stats[row*8 + w*2]     = ps[mt][r];
                stats[row*8 + w*2 + 1] = pq[mt][r];
            }
        }
        __syncthreads();
        float lnsc0 = ln2_s[col0], lnsc1 = ln2_s[col1];
        float lnbb0 = ln2_b[col0], lnbb1 = ln2_b[col1];
        #pragma unroll
        for (int mt = 0; mt < 2; mt++)
        #pragma unroll
        for (int r = 0; r < 4; r++) {
            int row = mt*16 + g*4 + r;
            float sm = stats[row*8+0] + stats[row*8+2] + stats[row*8+4] + stats[row*8+6];
            float sq = stats[row*8+1] + stats[row*8+3] + stats[row*8+5] + stats[row*8+7];
            float mean = sm * (1.0f/C_);
            float var = sq * (1.0f/C_) - mean*mean;
            float rs = rsqrtf(var + 1e-5f);
            float xn0 = (xres[mt][0][r] - mean) * rs * lnsc0 + lnbb0;
            float xn1 = (xres[mt][1][r] - mean) * rs * lnsc1 + lnbb1;
            int b0 = ((row*C_ + col0)*2) ^ ((row & 7) << 4);
            int b1 = ((row*C_ + col1)*2) ^ ((row & 7) << 4);
            *(unsigned short*)((char*)at + b0) = f2b(xn0);
            *(unsigned short*)((char*)at + b1) = f2b(xn1);
        }
    }
    __syncthreads();

    // ---- Phase D: FF1 -> fft (relu) ----
    {
        int nh = w*64;
        f32x4 acc1[2][4] = {};
        #pragma unroll
        for (int ks = 0; ks < 4; ks++) {
            int ka = ks*32 + g*8;
            bf16x8 a0 = ldfrag<C_>(at, lr, ka);
            bf16x8 a1 = ldfrag<C_>(at, 16 + lr, ka);
            #pragma unroll
            for (int nt = 0; nt < 4; nt++) {
                bf16x8 bb = *(const bf16x8*)(w1T + (size_t)(nh + nt*16 + lr)*C_ + ka);
                acc1[0][nt] = MFMA(a0, bb, acc1[0][nt]);
                acc1[1][nt] = MFMA(a1, bb, acc1[1][nt]);
            }
        }
        __syncthreads();
        #pragma unroll
        for (int mt = 0; mt < 2; mt++)
        #pragma unroll
        for (int nt = 0; nt < 4; nt++)
        #pragma unroll
        for (int r = 0; r < 4; r++) {
            int row = mt*16 + g*4 + r;
            int col = nh + nt*16 + lr;
            int byte = ((row*FF_ + col)*2) ^ ((row & 7) << 4);
            *(unsigned short*)((char*)fft + byte) = f2b(fmaxf(acc1[mt][nt][r], 0.f));
        }
    }
    __syncthreads();

    // ---- Phase E: FF2 + residual (regs) (+ final mask/skip) ----
    {
        int nq = w*32;
        f32x4 acc2[2][2] = {};
        #pragma unroll
        for (int ks = 0; ks < 8; ks++) {
            int ka = ks*32 + g*8;
            bf16x8 a0 = ldfrag<FF_>(fft, lr, ka);
            bf16x8 a1 = ldfrag<FF_>(fft, 16 + lr, ka);
            #pragma unroll
            for (int nt = 0; nt < 2; nt++) {
                bf16x8 bb = *(const bf16x8*)(w2T + (size_t)(nq + nt*16 + lr)*FF_ + ka);
                acc2[0][nt] = MFMA(a0, bb, acc2[0][nt]);
                acc2[1][nt] = MFMA(a1, bb, acc2[1][nt]);
            }
        }
        #pragma unroll
        for (int mt = 0; mt < 2; mt++)
        #pragma unroll
        for (int nt = 0; nt < 2; nt++)
        #pragma unroll
        for (int r = 0; r < 4; r++) {
            int row = mt*16 + g*4 + r;
            int col = nq + nt*16 + lr;
            size_t o = ((size_t)s*Q_ + row)*C_ + col;
            float v2 = xres[mt][nt][r] + acc2[mt][nt][r];
            if (qmask_opt) {
                v2 *= (float)qmask_opt[s*Q_ + row];
                skip_opt[o] = v2;
            }
            x[o] = v2;
            xres[mt][nt][r] = v2;
        }
    }
    if (!wqT_next) return;
    __syncthreads();

    // ================== LN1(next) (register-space) -> at + xn16 ==================
    {
        float ps[2][4], pq[2][4];
        #pragma unroll
        for (int mt = 0; mt < 2; mt++)
        #pragma unroll
        for (int r = 0; r < 4; r++) {
            float a = xres[mt][0][r], b = xres[mt][1][r];
            float sum = a + b, sq = a*a + b*b;
            #pragma unroll
            for (int m = 1; m <= 8; m <<= 1) { sum += __shfl_xor(sum, m); sq += __shfl_xor(sq, m); }
            ps[mt][r] = sum; pq[mt][r] = sq;
        }
        if (lr == 0) {
            #pragma unroll
            for (int mt = 0; mt < 2; mt++)
            #pragma unroll
            for (int r = 0; r < 4; r++) {
                int row = mt*16 + g*4 + r;
                stats[row*8 + w*2]     = ps[mt][r];
                stats[row*8 + w*2 + 1] = pq[mt][r];
            }
        }
        __syncthreads();
        float lnsc0 = ln1_s[col0], lnsc1 = ln1_s[col1];
        float lnbb0 = ln1_b[col0], lnbb1 = ln1_b[col1];
        #pragma unroll
        for (int mt = 0; mt < 2; mt++)
        #pragma unroll
        for (int r = 0; r < 4; r++) {
            int row = mt*16 + g*4 + r;
            float sm = stats[row*8+0] + stats[row*8+2] + stats[row*8+4] + stats[row*8+6];
            float sq = stats[row*8+1] + stats[row*8+3] + stats[row*8+5] + stats[row*8+7];
            float mean = sm * (1.0f/C_);
            float var = sq * (1.0f/C_) - mean*mean;
            float rs = rsqrtf(var + 1e-5f);
            float xn0 = (xres[mt][0][r] - mean) * rs * lnsc0 + lnbb0;
            float xn1 = (xres[mt][1][r] - mean) * rs * lnsc1 + lnbb1;
            unsigned short h0 = f2b(xn0), h1 = f2b(xn1);
            int b0 = ((row*C_ + col0)*2) ^ ((row & 7) << 4);
            int b1 = ((row*C_ + col1)*2) ^ ((row & 7) << 4);
            *(unsigned short*)((char*)at + b0) = h0;
            *(unsigned short*)((char*)at + b1) = h1;
            size_t gro = ((size_t)s*Q_ + row)*C_;
            xn16[gro + col0] = h0;
            xn16[gro + col1] = h1;
        }
    }
    __syncthreads();

    // ---- Phase G: qproj(next): wave w = head w ----
    {
        f32x4 acc3[2][2] = {};
        #pragma unroll
        for (int ks = 0; ks < 4; ks++) {
            int ka = ks*32 + g*8;
            bf16x8 a0 = ldfrag<C_>(at, lr, ka);
            bf16x8 a1 = ldfrag<C_>(at, 16 + lr, ka);
            #pragma unroll
            for (int nt = 0; nt < 2; nt++) {
                bf16x8 bb = *(const bf16x8*)(wqT_next + (size_t)(w*32 + nt*16 + lr)*C_ + ka);
                acc3[0][nt] = MFMA(a0, bb, acc3[0][nt]);
                acc3[1][nt] = MFMA(a1, bb, acc3[1][nt]);
            }
        }
        const float scale = 0.17677669529663687f;
        #pragma unroll
        for (int mt = 0; mt < 2; mt++)
        #pragma unroll
        for (int nt = 0; nt < 2; nt++)
        #pragma unroll
        for (int r = 0; r < 4; r++) {
            int row = mt*16 + g*4 + r;
            int dd = nt*16 + lr;
            qb16_out[(((size_t)s*H_ + w)*Q_ + row)*DH_ + dd] = f2b(acc3[mt][nt][r] * scale);
        }
    }
}

// ---------------- token aggregation via MFMA: 1 token/block, 256 thr ----------------
__global__ __launch_bounds__(256) void k_token_m(const float* __restrict__ x,
                                                 const int* __restrict__ q2a_idx,
                                                 const int* __restrict__ q2a_mask,
                                                 const int* __restrict__ dmask,
                                                 const ushort_t* __restrict__ waT,
                                                 float* __restrict__ out) {
    __shared__ unsigned short xs[32*C_];   // 8 KB, swizzled; rows 24-31 zero
    __shared__ float am[32];
    int tt = blockIdx.x, t = threadIdx.x;
    int w = t>>6, lane = t&63, lr = lane&15, g = lane>>4;

    for (int e8 = t; e8 < 32*(C_/8); e8 += 256) {
        int row = e8 >> 4, c8 = (e8 & 15)*8;
        bf16x8 o = {};
        if (row < A_) {
            int gm = q2a_mask[tt*A_ + row];
            if (gm) {
                const float4* xp = (const float4*)(x + (size_t)q2a_idx[tt*A_ + row]*C_ + c8);
                float4 f0 = xp[0], f1 = xp[1];
                o[0]=(short)f2b(f0.x); o[1]=(short)f2b(f0.y); o[2]=(short)f2b(f0.z); o[3]=(short)f2b(f0.w);
                o[4]=(short)f2b(f1.x); o[5]=(short)f2b(f1.y); o[6]=(short)f2b(f1.z); o[7]=(short)f2b(f1.w);
            }
        }
        int byte = ((row*C_ + c8)*2) ^ ((row & 7) << 4);
        *(bf16x8*)((char*)xs + byte) = o;
    }
    if (t < 32) am[t] = (t < A_) ? (float)dmask[tt*A_ + t] : 0.f;
    __syncthreads();

    f32x4 acc[2][6] = {};
    #pragma unroll
    for (int ks = 0; ks < 4; ks++) {
        int ka = ks*32 + g*8;
        bf16x8 a0 = ldfrag<C_>(xs, lr, ka);
        bf16x8 a1 = ldfrag<C_>(xs, 16 + lr, ka);
        #pragma unroll
        for (int nt = 0; nt < 6; nt++) {
            bf16x8 b = *(const bf16x8*)(waT + (size_t)(w*96 + nt*16 + lr)*C_ + ka);
            acc[0][nt] = MFMA(a0, b, acc[0][nt]);
            acc[1][nt] = MFMA(a1, b, acc[1][nt]);
        }
    }

    float amr[2][4];
    #pragma unroll
    for (int mt = 0; mt < 2; mt++)
    #pragma unroll
    for (int r = 0; r < 4; r++) amr[mt][r] = am[mt*16 + g*4 + r];
    float denom = 1e-10f;
    #pragma unroll
    for (int a = 0; a < A_; a++) denom += am[a];
    float invd = 1.0f / denom;
    #pragma unroll
    for (int nt = 0; nt < 6; nt++) {
        float v = 0.f;
        #pragma unroll
        for (int mt = 0; mt < 2; mt++)
        #pragma unroll
        for (int r = 0; r < 4; r++) v += amr[mt][r] * fmaxf(acc[mt][nt][r], 0.f);
        v += __shfl_xor(v, 16);
        v += __shfl_xor(v, 32);
        if (g == 0) out[(size_t)tt*PTC_ + w*96 + nt*16 + lr] = v * invd;
    }
}

extern "C" void kernel_launch(void* const* d_in, const int* in_sizes, int n_in,
                              void* d_out, int out_size, void* d_ws, size_t ws_size,
                              hipStream_t stream) {
    const int*   qmask    = (const int*)d_in[0];
    const int*   dmask    = (const int*)d_in[1];
    const int*   a2q_idx  = (const int*)d_in[2];
    const int*   a2q_mask = (const int*)d_in[3];
    const int*   q2k_idx  = (const int*)d_in[4];
    const int*   q2k_mask = (const int*)d_in[5];
    const int*   q2a_idx  = (const int*)d_in[6];
    const int*   q2a_mask = (const int*)d_in[7];
    const float* ta_act   = (const float*)d_in[8];
    const float* qsc      = (const float*)d_in[9];
    const float* pair     = (const float*)d_in[10];
    const int*   kmask    = (const int*)d_in[11];
    const float* ksc      = (const float*)d_in[12];
    const float* w_pos    = (const float*)d_in[13];
    const float* w_aggr   = (const float*)d_in[14];
    const float* ln1_s    = (const float*)d_in[15];
    const float* ln1_b    = (const float*)d_in[16];
    const float* wq       = (const float*)d_in[17];
    const float* wk       = (const float*)d_in[18];
    const float* wv       = (const float*)d_in[19];
    const float* wpair    = (const float*)d_in[20];
    const float* wo       = (const float*)d_in[21];
    const float* ln2_s    = (const float*)d_in[22];
    const float* ln2_b    = (const float*)d_in[23];
    const float* w1       = (const float*)d_in[24];
    const float* w2       = (const float*)d_in[25];
    float* out = (float*)d_out;

    float* ws = (float*)d_ws;
    float*    x      = ws;                                     // SQ*C f32
    ushort_t* xn16   = (ushort_t*)(x + (size_t)SQ_*C_);        // SQ*C bf16
    ushort_t* qb16   = xn16 + (size_t)SQ_*C_;                  // SQ*C bf16
    ushort_t* kb16   = qb16 + (size_t)SQ_*C_;                  // S*H*K*DH bf16
    ushort_t* vT16   = kb16 + (size_t)S_*H_*K_*DH_;            // S*H*DH*K bf16
    ushort_t* bias16 = vT16 + (size_t)S_*H_*K_*DH_;            // L*S*H*Q*K bf16
    ushort_t* woT16  = bias16 + (size_t)L_*S_*H_*Q_*K_;        // L*C*C
    ushort_t* wqT16  = woT16 + (size_t)L_*C_*C_;               // L*C*C
    ushort_t* wkT16  = wqT16 + (size_t)L_*C_*C_;               // L*C*C
    ushort_t* wvT16  = wkT16 + (size_t)L_*C_*C_;               // L*C*C
    ushort_t* w1T16  = wvT16 + (size_t)L_*C_*C_;               // L*C*FF
    ushort_t* w2T16  = w1T16 + (size_t)L_*C_*FF_;              // L*FF*C
    ushort_t* waT16  = w2T16 + (size_t)L_*FF_*C_;              // PTC*C
    ushort_t* ksc16  = waT16 + (size_t)PTC_*C_;                // S*K*C bf16

    k_prep<<<NB_WPREP + NB_INIT + NB_KSC, 256, 0, stream>>>(
        wq, wk, wv, w1, w2, wo, w_aggr,
        wqT16, wkT16, wvT16, w1T16, w2T16, woT16, waT16,
        a2q_idx, a2q_mask, qmask, ta_act, qsc, w_pos, x,
        ksc, ksc16);
    k_bias<<<S_*8, 256, 0, stream>>>(pair, wpair, bias16);
    k_lnqproj<<<SQ_/64, 256, 0, stream>>>(x, ln1_s, ln1_b, wqT16, xn16, qb16);

    for (int l = 0; l < L_; l++) {
        k_kv_m<<<SK_/64, 256, 0, stream>>>(xn16, q2k_idx, q2k_mask, ksc16,
                                           wkT16 + (size_t)l*C_*C_, wvT16 + (size_t)l*C_*C_,
                                           kb16, vT16);
        int last = (l == L_-1);
        k_mega<<<S_, 256, 0, stream>>>(qb16, kb16, vT16,
                                       bias16 + (size_t)l*S_*H_*Q_*K_, kmask,
                                       woT16 + (size_t)l*C_*C_, x,
                                       ln2_s + l*C_, ln2_b + l*C_,
                                       w1T16 + (size_t)l*C_*FF_, w2T16 + (size_t)l*FF_*C_,
                                       last ? nullptr : (ln1_s + (l+1)*C_),
                                       last ? nullptr : (ln1_b + (l+1)*C_),
                                       last ? nullptr : (wqT16 + (size_t)(l+1)*C_*C_),
                                       xn16, qb16,
                                       last ? qmask : nullptr,
                                       last ? (out + (size_t)T_*PTC_) : nullptr);
    }

    k_token_m<<<T_, 256, 0, stream>>>(x, q2a_idx, q2a_mask, dmask, waT16, out);
}

// Round 18
// 327.564 us; speedup vs baseline: 1.1209x; 1.1209x over previous
//
#include <hip/hip_runtime.h>
#include <hip/hip_bf16.h>

#define T_ 768
#define A_ 24
#define S_ 576
#define Q_ 32
#define K_ 128
#define C_ 128
#define H_ 4
#define DH_ 32
#define L_ 3
#define PAIR_ 16
#define PTC_ 384
#define FF_ 256
#define SQ_ (S_*Q_)
#define SK_ (S_*K_)

typedef __attribute__((ext_vector_type(8))) short bf16x8;
typedef __attribute__((ext_vector_type(4))) short bf16x4;
typedef __attribute__((ext_vector_type(4))) float f32x4;
typedef unsigned short ushort_t;

#define MFMA(a,b,c) __builtin_amdgcn_mfma_f32_16x16x32_bf16(a,b,c,0,0,0)

__device__ inline unsigned short f2b(float f) {
    union { float f; unsigned u; } v; v.f = f;
    unsigned u = v.u;
    return (unsigned short)((u + 0x7FFFu + ((u >> 16) & 1u)) >> 16);
}
__device__ inline float b2f(unsigned short b) {
    union { unsigned u; float f; } v; v.u = ((unsigned)b) << 16;
    return v.f;
}
__device__ inline float dot4(float4 a, float4 b) {
    return a.x*b.x + a.y*b.y + a.z*b.z + a.w*b.w;
}

// load one MFMA fragment (8 bf16 along k) from swizzled LDS tile with row-length KD
template<int KD>
__device__ inline bf16x8 ldfrag(const unsigned short* lds, int row, int k) {
    int byte = ((row*KD + k)*2) ^ ((row & 7) << 4);
    return *(const bf16x8*)((const char*)lds + byte);
}

// ---- LN over 64 rows (4 threads/row), from GLOBAL f32 -> swizzled LDS (+opt global bf16) ----
__device__ inline void ln_rows64(const float* __restrict__ x, size_t r0,
                                 const float* __restrict__ s, const float* __restrict__ b,
                                 unsigned short* at, ushort_t* __restrict__ xn16_opt) {
    int t = threadIdx.x;
    int row = t >> 2, q = t & 3;
    size_t gr = r0 + row;
    float v[32];
    const float4* xp = (const float4*)(x + gr*C_ + q*32);
    #pragma unroll
    for (int i = 0; i < 8; i++) {
        float4 f = xp[i];
        v[i*4]=f.x; v[i*4+1]=f.y; v[i*4+2]=f.z; v[i*4+3]=f.w;
    }
    float sum = 0.f;
    #pragma unroll
    for (int i = 0; i < 32; i++) sum += v[i];
    sum += __shfl_xor(sum, 1); sum += __shfl_xor(sum, 2);
    float mean = sum * (1.0f/C_);
    float sq = 0.f;
    #pragma unroll
    for (int i = 0; i < 32; i++) { float d = v[i]-mean; sq += d*d; }
    sq += __shfl_xor(sq, 1); sq += __shfl_xor(sq, 2);
    float rs = rsqrtf(sq * (1.0f/C_) + 1e-5f);
    #pragma unroll
    for (int i8 = 0; i8 < 4; i8++) {
        int c0 = q*32 + i8*8;
        const float4* sp = (const float4*)(s + c0);
        const float4* bp = (const float4*)(b + c0);
        float4 s0 = sp[0], s1 = sp[1], b0 = bp[0], b1 = bp[1];
        bf16x8 o;
        o[0] = (short)f2b((v[i8*8+0]-mean)*rs*s0.x + b0.x);
        o[1] = (short)f2b((v[i8*8+1]-mean)*rs*s0.y + b0.y);
        o[2] = (short)f2b((v[i8*8+2]-mean)*rs*s0.z + b0.z);
        o[3] = (short)f2b((v[i8*8+3]-mean)*rs*s0.w + b0.w);
        o[4] = (short)f2b((v[i8*8+4]-mean)*rs*s1.x + b1.x);
        o[5] = (short)f2b((v[i8*8+5]-mean)*rs*s1.y + b1.y);
        o[6] = (short)f2b((v[i8*8+6]-mean)*rs*s1.z + b1.z);
        o[7] = (short)f2b((v[i8*8+7]-mean)*rs*s1.w + b1.w);
        int byte = ((row*C_ + c0)*2) ^ ((row & 7) << 4);
        *(bf16x8*)((char*)at + byte) = o;
        if (xn16_opt) *(bf16x8*)(xn16_opt + gr*C_ + c0) = o;
    }
}

// ---------------- weight transpose helper ----------------
__device__ inline void wtr(const float* __restrict__ src, ushort_t* __restrict__ dst,
                           int e, int KD, int ND) {
    int l = e / (KD*ND), r = e % (KD*ND);
    int n = r / KD, k = r % KD;
    dst[e] = f2b(src[(size_t)l*KD*ND + (size_t)k*ND + n]);
}

#define NB_WPREP ((4*L_*C_*C_ + 2*L_*C_*FF_ + C_*PTC_)/256)
#define NB_INIT  ((SQ_*C_)/256)
#define NB_KSC   ((SK_*C_)/1024)

// ---------------- bias precompute (STANDALONE — needs full VGPR budget for 8x float4) ----------------
__global__ __launch_bounds__(256) void k_bias(const float* __restrict__ pair,
                                              const float* __restrict__ wpair,
                                              ushort_t* __restrict__ bias16) {
    __shared__ float wp[L_*H_][PAIR_];
    int t = threadIdx.x;
    if (t < L_*H_*PAIR_) {
        int lh = t >> 4, p = t & 15;
        wp[lh][p] = wpair[(lh>>2)*PAIR_*H_ + p*H_ + (lh&3)];
    }
    __syncthreads();
    int s = blockIdx.x >> 3, qg = blockIdx.x & 7;
    int qq = qg*4 + (t >> 6);
    int kk0 = (t & 63)*2;
    const float4* pp = (const float4*)(pair + (((size_t)s*Q_ + qq)*K_ + kk0)*PAIR_);
    float4 pa0 = pp[0], pa1 = pp[1], pa2 = pp[2], pa3 = pp[3];
    float4 pb0 = pp[4], pb1 = pp[5], pb2 = pp[6], pb3 = pp[7];
    #pragma unroll
    for (int lh = 0; lh < L_*H_; lh++) {
        const float4* w4 = (const float4*)&wp[lh][0];
        float4 w0 = w4[0], w1 = w4[1], w2 = w4[2], w3 = w4[3];
        float a = dot4(pa0,w0) + dot4(pa1,w1) + dot4(pa2,w2) + dot4(pa3,w3);
        float b = dot4(pb0,w0) + dot4(pb1,w1) + dot4(pb2,w2) + dot4(pb3,w3);
        unsigned pack = (unsigned)f2b(a) | ((unsigned)f2b(b) << 16);
        int l = lh >> 2, h = lh & 3;
        *(unsigned*)(bias16 + (((size_t)l*S_ + s)*H_ + h)*(Q_*K_) + qq*K_ + kk0) = pack;
    }
}

// ---------------- fused prep: weight transposes (incl. w_aggr) | init x | ksc->bf16 ----------------
__global__ __launch_bounds__(256) void k_prep(
    const float* __restrict__ wq, const float* __restrict__ wk, const float* __restrict__ wv,
    const float* __restrict__ w1, const float* __restrict__ w2, const float* __restrict__ wo,
    const float* __restrict__ w_aggr,
    ushort_t* __restrict__ wqT, ushort_t* __restrict__ wkT, ushort_t* __restrict__ wvT,
    ushort_t* __restrict__ w1T, ushort_t* __restrict__ w2T, ushort_t* __restrict__ woT,
    ushort_t* __restrict__ waT,
    const int* __restrict__ a2q_idx, const int* __restrict__ a2q_mask,
    const int* __restrict__ qmask, const float* __restrict__ ta_act,
    const float* __restrict__ qsc, const float* __restrict__ w_pos, float* __restrict__ x,
    const float* __restrict__ ksc, ushort_t* __restrict__ ksc16) {
    int blk = blockIdx.x, t = threadIdx.x;
    if (blk < NB_WPREP) {
        int e = blk * 256 + t;
        const int s_cc = L_*C_*C_;
        const int s_cf = L_*C_*FF_;
        if (e < s_cc)      { wtr(wq, wqT, e, C_, C_); return; }
        e -= s_cc;
        if (e < s_cc)      { wtr(wk, wkT, e, C_, C_); return; }
        e -= s_cc;
        if (e < s_cc)      { wtr(wv, wvT, e, C_, C_); return; }
        e -= s_cc;
        if (e < s_cf)      { wtr(w1, w1T, e, C_, FF_); return; }
        e -= s_cf;
        if (e < s_cf)      { wtr(w2, w2T, e, FF_, C_); return; }
        e -= s_cf;
        if (e < s_cc)      { wtr(wo, woT, e, C_, C_); return; }
        e -= s_cc;
        wtr(w_aggr, waT, e, C_, PTC_);
        return;
    }
    blk -= NB_WPREP;
    if (blk < NB_INIT) {
        int i = blk * 256 + t;
        int r = i / C_, c = i % C_;
        float v = 0.f;
        if (a2q_mask[r]) {
            int idx = a2q_idx[r];
            float p0 = ta_act[idx*3+0], p1 = ta_act[idx*3+1], p2 = ta_act[idx*3+2];
            v = p0 * w_pos[c] + p1 * w_pos[C_+c] + p2 * w_pos[2*C_+c];
        }
        v *= (float)qmask[r];
        x[i] = v + qsc[i];
        return;
    }
    blk -= NB_INIT;
    {
        int e4 = blk * 256 + t;
        float4 f = ((const float4*)ksc)[e4];
        bf16x4 o;
        o[0] = (short)f2b(f.x); o[1] = (short)f2b(f.y);
        o[2] = (short)f2b(f.z); o[3] = (short)f2b(f.w);
        *(bf16x4*)(ksc16 + (size_t)e4*4) = o;
    }
}

// ---------------- LN1 + q projection fused (layer 0 only) ----------------
__global__ __launch_bounds__(256) void k_lnqproj(const float* __restrict__ x,
                                                 const float* __restrict__ s, const float* __restrict__ b,
                                                 const ushort_t* __restrict__ wqT,
                                                 ushort_t* __restrict__ xn16,
                                                 ushort_t* __restrict__ qb16) {
    __shared__ unsigned short at[64*C_];   // 16 KB
    size_t r0 = (size_t)blockIdx.x * 64;
    ln_rows64(x, r0, s, b, at, xn16);
    __syncthreads();
    int t = threadIdx.x, wid = t>>6, lane = t&63, lr = lane&15, g = lane>>4;
    int mh = (wid&1)*32, nh = (wid>>1)*64;
    f32x4 acc[2][4] = {};
    #pragma unroll
    for (int ks = 0; ks < 4; ks++) {
        int ka = ks*32 + g*8;
        bf16x8 a0 = ldfrag<C_>(at, mh + lr, ka);
        bf16x8 a1 = ldfrag<C_>(at, mh + 16 + lr, ka);
        #pragma unroll
        for (int nt = 0; nt < 4; nt++) {
            bf16x8 bb = *(const bf16x8*)(wqT + (size_t)(nh + nt*16 + lr)*C_ + ka);
            acc[0][nt] = MFMA(a0, bb, acc[0][nt]);
            acc[1][nt] = MFMA(a1, bb, acc[1][nt]);
        }
    }
    const float scale = 0.17677669529663687f;  // 1/sqrt(32)
    #pragma unroll
    for (int mt = 0; mt < 2; mt++)
    #pragma unroll
    for (int nt = 0; nt < 4; nt++)
    #pragma unroll
    for (int r = 0; r < 4; r++) {
        int row = (int)r0 + mh + mt*16 + g*4 + r;
        int col = nh + nt*16 + lr;
        int s2 = row>>5, qq = row&31, h = col>>5, dd = col&31;
        qb16[(((size_t)s2*H_ + h)*Q_ + qq)*DH_ + dd] = f2b(acc[mt][nt][r] * scale);
    }
}

// ------- keys gather (16 KB LDS) + K/V projection; weights direct from global -------
__global__ __launch_bounds__(256) void k_kv_m(const ushort_t* __restrict__ xn16,
    const int* __restrict__ q2k_idx, const int* __restrict__ q2k_mask,
    const ushort_t* __restrict__ ksc16,
    const ushort_t* __restrict__ wkT, const ushort_t* __restrict__ wvT,
    ushort_t* __restrict__ kb16, ushort_t* __restrict__ vT16) {
    __shared__ unsigned short at[64*C_];   // 16 KB, swizzled
    int t = threadIdx.x, wid = t>>6, lane = t&63, lr = lane&15, g = lane>>4;
    int r0 = blockIdx.x * 64;
    for (int e8 = t; e8 < 64*(C_/8); e8 += 256) {
        int row = e8 >> 4, c8 = (e8 & 15)*8;
        int gr = r0 + row;
        bf16x8 kc8 = *(const bf16x8*)(ksc16 + (size_t)gr*C_ + c8);
        bf16x8 o;
        if (q2k_mask[gr]) {
            bf16x8 xv = *(const bf16x8*)(xn16 + (size_t)q2k_idx[gr]*C_ + c8);
            #pragma unroll
            for (int j = 0; j < 8; j++)
                o[j] = (short)f2b(b2f((unsigned short)xv[j]) + b2f((unsigned short)kc8[j]));
        } else {
            o = kc8;
        }
        int byte = ((row*C_ + c8)*2) ^ ((row & 7) << 4);
        *(bf16x8*)((char*)at + byte) = o;
    }
    __syncthreads();
    int mh = (wid&1)*32, nh = (wid>>1)*64;
    f32x4 acc[2][4][2] = {};
    #pragma unroll
    for (int ks = 0; ks < 4; ks++) {
        int ka = ks*32 + g*8;
        bf16x8 a0 = ldfrag<C_>(at, mh + lr, ka);
        bf16x8 a1 = ldfrag<C_>(at, mh + 16 + lr, ka);
        #pragma unroll
        for (int nt = 0; nt < 4; nt++) {
            bf16x8 bk = *(const bf16x8*)(wkT + (size_t)(nh + nt*16 + lr)*C_ + ka);
            bf16x8 bv = *(const bf16x8*)(wvT + (size_t)(nh + nt*16 + lr)*C_ + ka);
            acc[0][nt][0] = MFMA(a0, bk, acc[0][nt][0]);
            acc[1][nt][0] = MFMA(a1, bk, acc[1][nt][0]);
            acc[0][nt][1] = MFMA(a0, bv, acc[0][nt][1]);
            acc[1][nt][1] = MFMA(a1, bv, acc[1][nt][1]);
        }
    }
    #pragma unroll
    for (int mt = 0; mt < 2; mt++)
    #pragma unroll
    for (int nt = 0; nt < 4; nt++)
    #pragma unroll
    for (int r = 0; r < 4; r++) {
        int row = r0 + mh + mt*16 + g*4 + r;
        int col = nh + nt*16 + lr;
        int s = row>>7, kk = row&127, h = col>>5, dd = col&31;
        kb16[(((size_t)s*H_ + h)*K_ + kk)*DH_ + dd] = f2b(acc[mt][nt][0][r]);
        vT16[(((size_t)s*H_ + h)*DH_ + dd)*K_ + kk] = f2b(acc[mt][nt][1][r]);
    }
}

// ==== MEGA: attn + residual(regs) + LN2 + FF1 + FF2 (+ LN1'/qproj' or final mask) ====
// R14 form: x read at Phase B (short register lifetime — x-prefetch costs occupancy, R16/R17 data).
__global__ __launch_bounds__(256) void k_mega(
    const ushort_t* __restrict__ qb16_in, const ushort_t* __restrict__ kb16,
    const ushort_t* __restrict__ vT16, const ushort_t* __restrict__ bias16,
    const int* __restrict__ kmask_g, const ushort_t* __restrict__ woT16,
    float* __restrict__ x,
    const float* __restrict__ ln2_s, const float* __restrict__ ln2_b,
    const ushort_t* __restrict__ w1T, const ushort_t* __restrict__ w2T,
    const float* __restrict__ ln1_s, const float* __restrict__ ln1_b,
    const ushort_t* __restrict__ wqT_next,
    ushort_t* __restrict__ xn16, ushort_t* __restrict__ qb16_out,
    const int* __restrict__ qmask_opt, float* __restrict__ skip_opt) {
    __shared__ __align__(16) char smem[40960];
    unsigned short* BP    = (unsigned short*)smem;            // 4 planes x 8 KB (bias, then P)
    unsigned short* O_lds = (unsigned short*)(smem + 32768);  // 8 KB
    unsigned short* at    = (unsigned short*)smem;            // alias plane 0 (post-PV)
    unsigned short* fft   = (unsigned short*)(smem + 8192);   // alias planes 1-2 (post-PV)
    float*          stats = (float*)(smem + 32768);           // [32][8] after wo consumed O_lds

    int s = blockIdx.x, t = threadIdx.x;
    int w = t>>6, lane = t&63, lr = lane&15, g = lane>>4;

    // ---- Phase A: attention ----
    {
        const ushort_t* bb = bias16 + (size_t)s*H_*Q_*K_;
        for (int e8 = t; e8 < H_*Q_*K_/8; e8 += 256) {
            int h = e8 >> 9, rem = e8 & 511;
            int qq = rem >> 4, kk0 = (rem & 15)*8;
            bf16x8 v = *(const bf16x8*)(bb + h*(Q_*K_) + qq*K_ + kk0);
            int byte = ((qq*K_ + kk0)*2) ^ (((qq>>2)&3)<<5);
            *(bf16x8*)((char*)(BP + h*(Q_*K_)) + byte) = v;
        }
    }

    const ushort_t* qbase = qb16_in + ((size_t)(s*H_ + w)*Q_)*DH_;
    bf16x8 aq0 = *(const bf16x8*)(qbase + (size_t)lr*DH_ + g*8);
    bf16x8 aq1 = *(const bf16x8*)(qbase + (size_t)(16+lr)*DH_ + g*8);

    const ushort_t* kbase = kb16 + ((size_t)(s*H_ + w)*K_)*DH_;
    f32x4 acc[2][8] = {};
    #pragma unroll
    for (int nt = 0; nt < 8; nt++) {
        bf16x8 b = *(const bf16x8*)(kbase + (size_t)(nt*16+lr)*DH_ + g*8);
        acc[0][nt] = MFMA(aq0, b, acc[0][nt]);
        acc[1][nt] = MFMA(aq1, b, acc[1][nt]);
    }

    float km[8];
    #pragma unroll
    for (int nt = 0; nt < 8; nt++) km[nt] = (kmask_g[s*K_ + nt*16 + lr] - 1.0f) * 1e9f;

    __syncthreads();   // bias staged

    unsigned short* Pb = BP + w*(Q_*K_);
    #pragma unroll
    for (int mt = 0; mt < 2; mt++)
    #pragma unroll
    for (int r = 0; r < 4; r++) {
        int qq = mt*16 + g*4 + r;
        #pragma unroll
        for (int nt = 0; nt < 8; nt++) {
            int byte = ((qq*K_ + nt*16 + lr)*2) ^ (((qq>>2)&3)<<5);
            acc[mt][nt][r] += b2f(*(unsigned short*)((char*)Pb + byte)) + km[nt];
        }
    }

    float inv[2][4];
    #pragma unroll
    for (int mt = 0; mt < 2; mt++)
    #pragma unroll
    for (int r = 0; r < 4; r++) {
        float mx = acc[mt][0][r];
        #pragma unroll
        for (int nt = 1; nt < 8; nt++) mx = fmaxf(mx, acc[mt][nt][r]);
        #pragma unroll
        for (int m = 1; m <= 8; m <<= 1) mx = fmaxf(mx, __shfl_xor(mx, m));
        float sum = 0.f;
        #pragma unroll
        for (int nt = 0; nt < 8; nt++) {
            float e = __expf(acc[mt][nt][r] - mx);
            acc[mt][nt][r] = e;
            sum += e;
        }
        #pragma unroll
        for (int m = 1; m <= 8; m <<= 1) sum += __shfl_xor(sum, m);
        inv[mt][r] = 1.0f / sum;
    }

    #pragma unroll
    for (int mt = 0; mt < 2; mt++)
    #pragma unroll
    for (int r = 0; r < 4; r++) {
        int row = mt*16 + g*4 + r;
        #pragma unroll
        for (int nt = 0; nt < 8; nt++) {
            int byte = ((row*K_ + nt*16 + lr)*2) ^ ((row & 7) << 4);
            *(unsigned short*)((char*)Pb + byte) = f2b(acc[mt][nt][r]);
        }
    }

    const ushort_t* vbase = vT16 + ((size_t)(s*H_ + w)*DH_)*K_;
    f32x4 po[2][2] = {};
    #pragma unroll
    for (int ks = 0; ks < 4; ks++) {
        int kk0 = ks*32 + g*8;
        bf16x8 a0 = ldfrag<K_>(Pb, lr, kk0);
        bf16x8 a1 = ldfrag<K_>(Pb, 16 + lr, kk0);
        #pragma unroll
        for (int nt = 0; nt < 2; nt++) {
            bf16x8 b = *(const bf16x8*)(vbase + (size_t)(nt*16+lr)*K_ + kk0);
            po[0][nt] = MFMA(a0, b, po[0][nt]);
            po[1][nt] = MFMA(a1, b, po[1][nt]);
        }
    }

    #pragma unroll
    for (int mt = 0; mt < 2; mt++)
    #pragma unroll
    for (int nt = 0; nt < 2; nt++)
    #pragma unroll
    for (int r = 0; r < 4; r++) {
        int row = mt*16 + g*4 + r;
        int col = w*32 + nt*16 + lr;
        int byte = ((row*C_ + col)*2) ^ ((row & 7) << 4);
        *(unsigned short*)((char*)O_lds + byte) = f2b(po[mt][nt][r] * inv[mt][r]);
    }
    __syncthreads();

    f32x4 fo[2][2] = {};
    #pragma unroll
    for (int ks = 0; ks < 4; ks++) {
        int k0 = ks*32 + g*8;
        bf16x8 a0 = ldfrag<C_>(O_lds, lr, k0);
        bf16x8 a1 = ldfrag<C_>(O_lds, 16 + lr, k0);
        #pragma unroll
        for (int nt = 0; nt < 2; nt++) {
            bf16x8 b = *(const bf16x8*)(woT16 + (size_t)(w*32 + nt*16 + lr)*C_ + k0);
            fo[0][nt] = MFMA(a0, b, fo[0][nt]);
            fo[1][nt] = MFMA(a1, b, fo[1][nt]);
        }
    }

    // ---- Phase B: residual into REGISTERS ----
    float xres[2][2][4];
    #pragma unroll
    for (int mt = 0; mt < 2; mt++)
    #pragma unroll
    for (int nt = 0; nt < 2; nt++)
    #pragma unroll
    for (int r = 0; r < 4; r++) {
        int row = mt*16 + g*4 + r;
        int col = w*32 + nt*16 + lr;
        xres[mt][nt][r] = x[((size_t)s*Q_ + row)*C_ + col] + fo[mt][nt][r];
    }
    __syncthreads();   // all PV/wo LDS reads done -> BP + O_lds reusable

    int col0 = w*32 + lr, col1 = w*32 + 16 + lr;

    // ================== LN2 (register-space) -> at ==================
    {
        float ps[2][4], pq[2][4];
        #pragma unroll
        for (int mt = 0; mt < 2; mt++)
        #pragma unroll
        for (int r = 0; r < 4; r++) {
            float a = xres[mt][0][r], b = xres[mt][1][r];
            float sum = a + b, sq = a*a + b*b;
            #pragma unroll
            for (int m = 1; m <= 8; m <<= 1) { sum += __shfl_xor(sum, m); sq += __shfl_xor(sq, m); }
            ps[mt][r] = sum; pq[mt][r] = sq;
        }
        if (lr == 0) {
            #pragma unroll
            for (int mt = 0; mt < 2; mt++)
            #pragma unroll
            for (int r = 0; r < 4; r++) {
                int row = mt*16 + g*4 + r;
                stats[row*8 + w*2]     = ps[mt][r];
                stats[row*8 + w*2 + 1] = pq[mt][r];
            }
        }
        __syncthreads();
        float lnsc0 = ln2_s[col0], lnsc1 = ln2_s[col1];
        float lnbb0 = ln2_b[col0], lnbb1 = ln2_b[col1];
        #pragma unroll
        for (int mt = 0; mt < 2; mt++)
        #pragma unroll
        for (int r = 0; r < 4; r++) {
            int row = mt*16 + g*4 + r;
            float sm = stats[row*8+0] + stats[row*8+2] + stats[row*8+4] + stats[row*8+6];
            float sq = stats[row*8+1] + stats[row*8+3] + stats[row*8+5] + stats[row*8+7];
            float mean = sm * (1.0f/C_);
            float var = sq * (1.0f/C_) - mean*mean;
            float rs = rsqrtf(var + 1e-5f);
            float xn0 = (xres[mt][0][r] - mean) * rs * lnsc0 + lnbb0;
            float xn1 = (xres[mt][1][r] - mean) * rs * lnsc1 + lnbb1;
            int b0 = ((row*C_ + col0)*2) ^ ((row & 7) << 4);
            int b1 = ((row*C_ + col1)*2) ^ ((row & 7) << 4);
            *(unsigned short*)((char*)at + b0) = f2b(xn0);
            *(unsigned short*)((char*)at + b1) = f2b(xn1);
        }
    }
    __syncthreads();

    // ---- Phase D: FF1 -> fft (relu) ----
    {
        int nh = w*64;
        f32x4 acc1[2][4] = {};
        #pragma unroll
        for (int ks = 0; ks < 4; ks++) {
            int ka = ks*32 + g*8;
            bf16x8 a0 = ldfrag<C_>(at, lr, ka);
            bf16x8 a1 = ldfrag<C_>(at, 16 + lr, ka);
            #pragma unroll
            for (int nt = 0; nt < 4; nt++) {
                bf16x8 bb = *(const bf16x8*)(w1T + (size_t)(nh + nt*16 + lr)*C_ + ka);
                acc1[0][nt] = MFMA(a0, bb, acc1[0][nt]);
                acc1[1][nt] = MFMA(a1, bb, acc1[1][nt]);
            }
        }
        __syncthreads();
        #pragma unroll
        for (int mt = 0; mt < 2; mt++)
        #pragma unroll
        for (int nt = 0; nt < 4; nt++)
        #pragma unroll
        for (int r = 0; r < 4; r++) {
            int row = mt*16 + g*4 + r;
            int col = nh + nt*16 + lr;
            int byte = ((row*FF_ + col)*2) ^ ((row & 7) << 4);
            *(unsigned short*)((char*)fft + byte) = f2b(fmaxf(acc1[mt][nt][r], 0.f));
        }
    }
    __syncthreads();

    // ---- Phase E: FF2 + residual (regs) (+ final mask/skip) ----
    {
        int nq = w*32;
        f32x4 acc2[2][2] = {};
        #pragma unroll
        for (int ks = 0; ks < 8; ks++) {
            int ka = ks*32 + g*8;
            bf16x8 a0 = ldfrag<FF_>(fft, lr, ka);
            bf16x8 a1 = ldfrag<FF_>(fft, 16 + lr, ka);
            #pragma unroll
            for (int nt = 0; nt < 2; nt++) {
                bf16x8 bb = *(const bf16x8*)(w2T + (size_t)(nq + nt*16 + lr)*FF_ + ka);
                acc2[0][nt] = MFMA(a0, bb, acc2[0][nt]);
                acc2[1][nt] = MFMA(a1, bb, acc2[1][nt]);
            }
        }
        #pragma unroll
        for (int mt = 0; mt < 2; mt++)
        #pragma unroll
        for (int nt = 0; nt < 2; nt++)
        #pragma unroll
        for (int r = 0; r < 4; r++) {
            int row = mt*16 + g*4 + r;
            int col = nq + nt*16 + lr;
            size_t o = ((size_t)s*Q_ + row)*C_ + col;
            float v2 = xres[mt][nt][r] + acc2[mt][nt][r];
            if (qmask_opt) {
                v2 *= (float)qmask_opt[s*Q_ + row];
                skip_opt[o] = v2;
            }
            x[o] = v2;
            xres[mt][nt][r] = v2;
        }
    }
    if (!wqT_next) return;
    __syncthreads();

    // ================== LN1(next) (register-space) -> at + xn16 ==================
    {
        float ps[2][4], pq[2][4];
        #pragma unroll
        for (int mt = 0; mt < 2; mt++)
        #pragma unroll
        for (int r = 0; r < 4; r++) {
            float a = xres[mt][0][r], b = xres[mt][1][r];
            float sum = a + b, sq = a*a + b*b;
            #pragma unroll
            for (int m = 1; m <= 8; m <<= 1) { sum += __shfl_xor(sum, m); sq += __shfl_xor(sq, m); }
            ps[mt][r] = sum; pq[mt][r] = sq;
        }
        if (lr == 0) {
            #pragma unroll
            for (int mt = 0; mt < 2; mt++)
            #pragma unroll
            for (int r = 0; r < 4; r++) {
                int row = mt*16 + g*4 + r;
                stats[row*8 + w*2]     = ps[mt][r];
                stats[row*8 + w*2 + 1] = pq[mt][r];
            }
        }
        __syncthreads();
        float lnsc0 = ln1_s[col0], lnsc1 = ln1_s[col1];
        float lnbb0 = ln1_b[col0], lnbb1 = ln1_b[col1];
        #pragma unroll
        for (int mt = 0; mt < 2; mt++)
        #pragma unroll
        for (int r = 0; r < 4; r++) {
            int row = mt*16 + g*4 + r;
            float sm = stats[row*8+0] + stats[row*8+2] + stats[row*8+4] + stats[row*8+6];
            float sq = stats[row*8+1] + stats[row*8+3] + stats[row*8+5] + stats[row*8+7];
            float mean = sm * (1.0f/C_);
            float var = sq * (1.0f/C_) - mean*mean;
            float rs = rsqrtf(var + 1e-5f);
            float xn0 = (xres[mt][0][r] - mean) * rs * lnsc0 + lnbb0;
            float xn1 = (xres[mt][1][r] - mean) * rs * lnsc1 + lnbb1;
            unsigned short h0 = f2b(xn0), h1 = f2b(xn1);
            int b0 = ((row*C_ + col0)*2) ^ ((row & 7) << 4);
            int b1 = ((row*C_ + col1)*2) ^ ((row & 7) << 4);
            *(unsigned short*)((char*)at + b0) = h0;
            *(unsigned short*)((char*)at + b1) = h1;
            size_t gro = ((size_t)s*Q_ + row)*C_;
            xn16[gro + col0] = h0;
            xn16[gro + col1] = h1;
        }
    }
    __syncthreads();

    // ---- Phase G: qproj(next): wave w = head w ----
    {
        f32x4 acc3[2][2] = {};
        #pragma unroll
        for (int ks = 0; ks < 4; ks++) {
            int ka = ks*32 + g*8;
            bf16x8 a0 = ldfrag<C_>(at, lr, ka);
            bf16x8 a1 = ldfrag<C_>(at, 16 + lr, ka);
            #pragma unroll
            for (int nt = 0; nt < 2; nt++) {
                bf16x8 bb = *(const bf16x8*)(wqT_next + (size_t)(w*32 + nt*16 + lr)*C_ + ka);
                acc3[0][nt] = MFMA(a0, bb, acc3[0][nt]);
                acc3[1][nt] = MFMA(a1, bb, acc3[1][nt]);
            }
        }
        const float scale = 0.17677669529663687f;
        #pragma unroll
        for (int mt = 0; mt < 2; mt++)
        #pragma unroll
        for (int nt = 0; nt < 2; nt++)
        #pragma unroll
        for (int r = 0; r < 4; r++) {
            int row = mt*16 + g*4 + r;
            int dd = nt*16 + lr;
            qb16_out[(((size_t)s*H_ + w)*Q_ + row)*DH_ + dd] = f2b(acc3[mt][nt][r] * scale);
        }
    }
}

// ---------------- token aggregation via MFMA: 1 token/block, 256 thr ----------------
__global__ __launch_bounds__(256) void k_token_m(const float* __restrict__ x,
                                                 const int* __restrict__ q2a_idx,
                                                 const int* __restrict__ q2a_mask,
                                                 const int* __restrict__ dmask,
                                                 const ushort_t* __restrict__ waT,
                                                 float* __restrict__ out) {
    __shared__ unsigned short xs[32*C_];   // 8 KB, swizzled; rows 24-31 zero
    __shared__ float am[32];
    int tt = blockIdx.x, t = threadIdx.x;
    int w = t>>6, lane = t&63, lr = lane&15, g = lane>>4;

    for (int e8 = t; e8 < 32*(C_/8); e8 += 256) {
        int row = e8 >> 4, c8 = (e8 & 15)*8;
        bf16x8 o = {};
        if (row < A_) {
            int gm = q2a_mask[tt*A_ + row];
            if (gm) {
                const float4* xp = (const float4*)(x + (size_t)q2a_idx[tt*A_ + row]*C_ + c8);
                float4 f0 = xp[0], f1 = xp[1];
                o[0]=(short)f2b(f0.x); o[1]=(short)f2b(f0.y); o[2]=(short)f2b(f0.z); o[3]=(short)f2b(f0.w);
                o[4]=(short)f2b(f1.x); o[5]=(short)f2b(f1.y); o[6]=(short)f2b(f1.z); o[7]=(short)f2b(f1.w);
            }
        }
        int byte = ((row*C_ + c8)*2) ^ ((row & 7) << 4);
        *(bf16x8*)((char*)xs + byte) = o;
    }
    if (t < 32) am[t] = (t < A_) ? (float)dmask[tt*A_ + t] : 0.f;
    __syncthreads();

    f32x4 acc[2][6] = {};
    #pragma unroll
    for (int ks = 0; ks < 4; ks++) {
        int ka = ks*32 + g*8;
        bf16x8 a0 = ldfrag<C_>(xs, lr, ka);
        bf16x8 a1 = ldfrag<C_>(xs, 16 + lr, ka);
        #pragma unroll
        for (int nt = 0; nt < 6; nt++) {
            bf16x8 b = *(const bf16x8*)(waT + (size_t)(w*96 + nt*16 + lr)*C_ + ka);
            acc[0][nt] = MFMA(a0, b, acc[0][nt]);
            acc[1][nt] = MFMA(a1, b, acc[1][nt]);
        }
    }

    float amr[2][4];
    #pragma unroll
    for (int mt = 0; mt < 2; mt++)
    #pragma unroll
    for (int r = 0; r < 4; r++) amr[mt][r] = am[mt*16 + g*4 + r];
    float denom = 1e-10f;
    #pragma unroll
    for (int a = 0; a < A_; a++) denom += am[a];
    float invd = 1.0f / denom;
    #pragma unroll
    for (int nt = 0; nt < 6; nt++) {
        float v = 0.f;
        #pragma unroll
        for (int mt = 0; mt < 2; mt++)
        #pragma unroll
        for (int r = 0; r < 4; r++) v += amr[mt][r] * fmaxf(acc[mt][nt][r], 0.f);
        v += __shfl_xor(v, 16);
        v += __shfl_xor(v, 32);
        if (g == 0) out[(size_t)tt*PTC_ + w*96 + nt*16 + lr] = v * invd;
    }
}

extern "C" void kernel_launch(void* const* d_in, const int* in_sizes, int n_in,
                              void* d_out, int out_size, void* d_ws, size_t ws_size,
                              hipStream_t stream) {
    const int*   qmask    = (const int*)d_in[0];
    const int*   dmask    = (const int*)d_in[1];
    const int*   a2q_idx  = (const int*)d_in[2];
    const int*   a2q_mask = (const int*)d_in[3];
    const int*   q2k_idx  = (const int*)d_in[4];
    const int*   q2k_mask = (const int*)d_in[5];
    const int*   q2a_idx  = (const int*)d_in[6];
    const int*   q2a_mask = (const int*)d_in[7];
    const float* ta_act   = (const float*)d_in[8];
    const float* qsc      = (const float*)d_in[9];
    const float* pair     = (const float*)d_in[10];
    const int*   kmask    = (const int*)d_in[11];
    const float* ksc      = (const float*)d_in[12];
    const float* w_pos    = (const float*)d_in[13];
    const float* w_aggr   = (const float*)d_in[14];
    const float* ln1_s    = (const float*)d_in[15];
    const float* ln1_b    = (const float*)d_in[16];
    const float* wq       = (const float*)d_in[17];
    const float* wk       = (const float*)d_in[18];
    const float* wv       = (const float*)d_in[19];
    const float* wpair    = (const float*)d_in[20];
    const float* wo       = (const float*)d_in[21];
    const float* ln2_s    = (const float*)d_in[22];
    const float* ln2_b    = (const float*)d_in[23];
    const float* w1       = (const float*)d_in[24];
    const float* w2       = (const float*)d_in[25];
    float* out = (float*)d_out;

    float* ws = (float*)d_ws;
    float*    x      = ws;                                     // SQ*C f32
    ushort_t* xn16   = (ushort_t*)(x + (size_t)SQ_*C_);        // SQ*C bf16
    ushort_t* qb16   = xn16 + (size_t)SQ_*C_;                  // SQ*C bf16
    ushort_t* kb16   = qb16 + (size_t)SQ_*C_;                  // S*H*K*DH bf16
    ushort_t* vT16   = kb16 + (size_t)S_*H_*K_*DH_;            // S*H*DH*K bf16
    ushort_t* bias16 = vT16 + (size_t)S_*H_*K_*DH_;            // L*S*H*Q*K bf16
    ushort_t* woT16  = bias16 + (size_t)L_*S_*H_*Q_*K_;        // L*C*C
    ushort_t* wqT16  = woT16 + (size_t)L_*C_*C_;               // L*C*C
    ushort_t* wkT16  = wqT16 + (size_t)L_*C_*C_;               // L*C*C
    ushort_t* wvT16  = wkT16 + (size_t)L_*C_*C_;               // L*C*C
    ushort_t* w1T16  = wvT16 + (size_t)L_*C_*C_;               // L*C*FF
    ushort_t* w2T16  = w1T16 + (size_t)L_*C_*FF_;              // L*FF*C
    ushort_t* waT16  = w2T16 + (size_t)L_*FF_*C_;              // PTC*C
    ushort_t* ksc16  = waT16 + (size_t)PTC_*C_;                // S*K*C bf16

    k_prep<<<NB_WPREP + NB_INIT + NB_KSC, 256, 0, stream>>>(
        wq, wk, wv, w1, w2, wo, w_aggr,
        wqT16, wkT16, wvT16, w1T16, w2T16, woT16, waT16,
        a2q_idx, a2q_mask, qmask, ta_act, qsc, w_pos, x,
        ksc, ksc16);
    k_bias<<<S_*8, 256, 0, stream>>>(pair, wpair, bias16);
    k_lnqproj<<<SQ_/64, 256, 0, stream>>>(x, ln1_s, ln1_b, wqT16, xn16, qb16);

    for (int l = 0; l < L_; l++) {
        k_kv_m<<<SK_/64, 256, 0, stream>>>(xn16, q2k_idx, q2k_mask, ksc16,
                                           wkT16 + (size_t)l*C_*C_, wvT16 + (size_t)l*C_*C_,
                                           kb16, vT16);
        int last = (l == L_-1);
        k_mega<<<S_, 256, 0, stream>>>(qb16, kb16, vT16,
                                       bias16 + (size_t)l*S_*H_*Q_*K_, kmask,
                                       woT16 + (size_t)l*C_*C_, x,
                                       ln2_s + l*C_, ln2_b + l*C_,
                                       w1T16 + (size_t)l*C_*FF_, w2T16 + (size_t)l*FF_*C_,
                                       last ? nullptr : (ln1_s + (l+1)*C_),
                                       last ? nullptr : (ln1_b + (l+1)*C_),
                                       last ? nullptr : (wqT16 + (size_t)(l+1)*C_*C_),
                                       xn16, qb16,
                                       last ? qmask : nullptr,
                                       last ? (out + (size_t)T_*PTC_) : nullptr);
    }

    k_token_m<<<T_, 256, 0, stream>>>(x, q2a_idx, q2a_mask, dmask, waT16, out);
}